// Round 1
// baseline (45.477 us; speedup 1.0000x reference)
//
#include <hip/hip_runtime.h>

// LIF feed-forward scan: x[T,B,N] -> (spikes[T,B,N], v_T[B,N], i_T[B,N])
// T=256, B=32, N=4096. State per element kept in registers across the scan.
//
// Constants (LIFParameters):
//   dv = 0.1f * ((0 - v) + i);  v_dec = v + dv
//   i_dec = i - 0.2f * i
//   z = (v_dec > 1.0f)
//   v_new = z ? 0 : v_dec;  i_new = i_dec + x_t
//
// Op order replicates the fp32 reference exactly; FMA contraction disabled
// so spike threshold comparisons are bit-identical to numpy.

#define TSTEPS 256
#define BN     131072            // B*N = 32*4096
#define BN2    (BN / 2)          // float2 groups = 65536

__global__ __launch_bounds__(256) void lif_kernel(
    const float2* __restrict__ x,
    float2* __restrict__ spikes,
    float2* __restrict__ v_out,
    float2* __restrict__ i_out)
{
#pragma clang fp contract(off)
    const int idx = blockIdx.x * blockDim.x + threadIdx.x;   // [0, BN2)

    float vx = 0.0f, vy = 0.0f;   // v state (V_LEAK = 0)
    float ix = 0.0f, iy = 0.0f;   // i state

    const float2* xp = x + idx;
    float2*       sp = spikes + idx;

#pragma unroll 4
    for (int t = 0; t < TSTEPS; ++t) {
        const float2 xt = xp[(size_t)t * BN2];

        // lane element 0
        float dv0 = 0.1f * ((0.0f - vx) + ix);
        float vd0 = vx + dv0;
        float id0 = ix - 0.2f * ix;
        bool  s0  = (vd0 > 1.0f);
        vx = s0 ? 0.0f : vd0;
        ix = id0 + xt.x;

        // lane element 1
        float dv1 = 0.1f * ((0.0f - vy) + iy);
        float vd1 = vy + dv1;
        float id1 = iy - 0.2f * iy;
        bool  s1  = (vd1 > 1.0f);
        vy = s1 ? 0.0f : vd1;
        iy = id1 + xt.y;

        float2 z;
        z.x = s0 ? 1.0f : 0.0f;
        z.y = s1 ? 1.0f : 0.0f;
        sp[(size_t)t * BN2] = z;
    }

    v_out[idx] = make_float2(vx, vy);
    i_out[idx] = make_float2(ix, iy);
}

extern "C" void kernel_launch(void* const* d_in, const int* in_sizes, int n_in,
                              void* d_out, int out_size, void* d_ws, size_t ws_size,
                              hipStream_t stream)
{
    const float* x = (const float*)d_in[0];
    float* out = (float*)d_out;

    float* spikes = out;                              // T*B*N
    float* v_out  = out + (size_t)TSTEPS * BN;        // B*N
    float* i_out  = v_out + BN;                       // B*N

    dim3 grid(BN2 / 256);   // 256 blocks
    dim3 block(256);
    lif_kernel<<<grid, block, 0, stream>>>(
        (const float2*)x, (float2*)spikes, (float2*)v_out, (float2*)i_out);
}